// Round 12
// baseline (2210.183 us; speedup 1.0000x reference)
//
#include <hip/hip_runtime.h>
#include <hip/hip_bf16.h>
#include <math.h>

#define N_NODES 50000
#define N_EDGES 1600000
#define IN_DIM  128
#define HID     64
#define EPB     4096   // edges per sort block
#define NBLK    391    // ceil(N_EDGES / EPB)
#define NB2     782    // ceil(N_NODES / 64) buckets of 64 nodes
#define ASTR    68     // padded LDS accumulator stride (breaks bank aliasing)
static constexpr float EPS = 1e-6f;

typedef __attribute__((ext_vector_type(8))) short          short8;   // 8 bf16
typedef __attribute__((ext_vector_type(4))) float          f32x4;
typedef __attribute__((ext_vector_type(2))) float          f32x2;

__device__ __forceinline__ unsigned short f2bf(float f) {   // round-nearest-even
    union { float f; unsigned int i; } c; c.f = f;
    unsigned int r = c.i + 0x7FFFu + ((c.i >> 16) & 1u);
    return (unsigned short)(r >> 16);
}
__device__ __forceinline__ unsigned char f2fp8(float f) {   // OCP e4m3, HW cvt
    int p = __builtin_amdgcn_cvt_pk_fp8_f32(f, f, 0, false);
    return (unsigned char)(p & 0xff);
}
// hi-half selector must be a compile-time constant -> template parameter
template <bool HI>
__device__ __forceinline__ f32x2 fp8pair(int w) {
#if __has_builtin(__builtin_amdgcn_cvt_pk_f32_fp8)
    return __builtin_amdgcn_cvt_pk_f32_fp8(w, HI);
#else
    return (f32x2){__builtin_amdgcn_cvt_f32_fp8(w, HI ? 2 : 0),
                   __builtin_amdgcn_cvt_f32_fp8(w, HI ? 3 : 1)};
#endif
}

// ==== weight packing =========================================================

template <int K>
__device__ __forceinline__ void pack_body(const float* __restrict__ wS,
                                          const float* __restrict__ wN,
                                          unsigned short* __restrict__ pS,
                                          unsigned short* __restrict__ pN, int blk) {
    constexpr int NSLOT = (K / 32) * 4 * 64;
    int slot = blk * 256 + (int)threadIdx.x;
    if (slot >= NSLOT) return;
    int lane = slot & 63;
    int ct   = slot >> 6;
    int t    = ct & 3;
    int c    = ct >> 2;
    int m    = lane & 15;
    int quad = lane >> 4;
    int col  = t * 16 + m;
#pragma unroll
    for (int j = 0; j < 8; ++j) {
        int k = c * 32 + quad * 8 + j;
        pS[slot * 8 + j] = f2bf(wS[k * 64 + col]);
        pN[slot * 8 + j] = f2bf(wN[k * 64 + col]);
    }
}

// ==== CSR-lite build: bucket (64-node) counting sort =========================

// blocks 0..NBLK-1: per-block bucket histogram; blocks NBLK..NBLK+7: weight pack
__global__ __launch_bounds__(256) void bucket_count_pack(
    const int* __restrict__ ei, int* __restrict__ blockCounts,
    const float* __restrict__ w0s, const float* __restrict__ w0n,
    const float* __restrict__ w1s, const float* __restrict__ w1n,
    const float* __restrict__ w2s, const float* __restrict__ w2n,
    unsigned short* __restrict__ p0S, unsigned short* __restrict__ p0N,
    unsigned short* __restrict__ p1S, unsigned short* __restrict__ p1N,
    unsigned short* __restrict__ p2S, unsigned short* __restrict__ p2N) {
    if (blockIdx.x >= NBLK) {
        int blk = blockIdx.x - NBLK;
        if (blk < 4)      pack_body<IN_DIM>(w0s, w0n, p0S, p0N, blk);
        else if (blk < 6) pack_body<HID>(w1s, w1n, p1S, p1N, blk - 4);
        else              pack_body<HID>(w2s, w2n, p2S, p2N, blk - 6);
        return;
    }
    __shared__ int hist[NB2];
    for (int i = threadIdx.x; i < NB2; i += 256) hist[i] = 0;
    __syncthreads();
    int base = blockIdx.x * EPB;
    int lim  = min(EPB, N_EDGES - base);
    for (int i = threadIdx.x; i < lim; i += 256)
        atomicAdd(&hist[ei[N_EDGES + base + i] >> 6], 1);
    __syncthreads();
    for (int b = threadIdx.x; b < NB2; b += 256)
        blockCounts[blockIdx.x * NB2 + b] = hist[b];
}

// ==== dual GEMM body =========================================================
// hs = A@wS (fp32 out), hn = A@wN (fp8 e4m3 out)
template <int K, bool F32IN>
__device__ __forceinline__ void gemm_body(
    const void* __restrict__ Av,
    const unsigned short* __restrict__ pS,
    const unsigned short* __restrict__ pN,
    float* __restrict__ hs, unsigned char* __restrict__ hnq, int blk) {
    constexpr int NC = K / 32;
    int lane = threadIdx.x & 63;
    int wv   = threadIdx.x >> 6;
    int tile = blk * 4 + wv;
    if (tile >= N_NODES / 16) return;
    int m    = lane & 15;
    int quad = lane >> 4;

    const short8* pSf = (const short8*)pS;
    const short8* pNf = (const short8*)pN;

    f32x4 accS[4], accN[4];
#pragma unroll
    for (int t = 0; t < 4; ++t) {
        accS[t] = (f32x4){0.f, 0.f, 0.f, 0.f};
        accN[t] = (f32x4){0.f, 0.f, 0.f, 0.f};
    }
#pragma unroll
    for (int c = 0; c < NC; ++c) {
        short8 a;
        if constexpr (F32IN) {
            const float* Af = (const float*)Av + ((size_t)tile * 16 + m) * K + quad * 8 + c * 32;
            f32x4 a0 = *(const f32x4*)Af;
            f32x4 a1 = *(const f32x4*)(Af + 4);
#pragma unroll
            for (int k = 0; k < 4; ++k) a[k]     = (short)f2bf(a0[k]);
#pragma unroll
            for (int k = 0; k < 4; ++k) a[k + 4] = (short)f2bf(a1[k]);
        } else {
            const short8* Af = (const short8*)((const unsigned short*)Av +
                               ((size_t)tile * 16 + m) * K + quad * 8);
            a = Af[c * 4];
        }
#pragma unroll
        for (int t = 0; t < 4; ++t) {
            short8 bs = pSf[(c * 4 + t) * 64 + lane];
            short8 bn = pNf[(c * 4 + t) * 64 + lane];
            accS[t] = __builtin_amdgcn_mfma_f32_16x16x32_bf16(a, bs, accS[t], 0, 0, 0);
            accN[t] = __builtin_amdgcn_mfma_f32_16x16x32_bf16(a, bn, accN[t], 0, 0, 0);
        }
    }
    int row0 = tile * 16 + quad * 4;
#pragma unroll
    for (int t = 0; t < 4; ++t) {
#pragma unroll
        for (int r = 0; r < 4; ++r) {
            size_t o = (size_t)(row0 + r) * HID + t * 16 + m;
            hs[o]  = accS[t][r];
            hnq[o] = f2fp8(accN[t][r]);
        }
    }
}

// blocks 0..NB2-1: col_sum; blocks NB2.. : layer-0 GEMM (independent overlap)
__global__ __launch_bounds__(256) void col_sum_gemm0(
    const int* __restrict__ blockCounts, int* __restrict__ totals,
    const float* __restrict__ x,
    const unsigned short* __restrict__ p0S, const unsigned short* __restrict__ p0N,
    float* __restrict__ hs, unsigned char* __restrict__ hnq) {
    if (blockIdx.x >= NB2) {
        gemm_body<IN_DIM, true>(x, p0S, p0N, hs, hnq, blockIdx.x - NB2);
        return;
    }
    __shared__ int ws[4];
    int b = blockIdx.x;
    int s = 0;
    for (int i = threadIdx.x; i < NBLK; i += 256) s += blockCounts[i * NB2 + b];
#pragma unroll
    for (int off = 32; off >= 1; off >>= 1) s += __shfl_xor(s, off, 64);
    if ((threadIdx.x & 63) == 0) ws[threadIdx.x >> 6] = s;
    __syncthreads();
    if (threadIdx.x == 0) totals[b] = ws[0] + ws[1] + ws[2] + ws[3];
}

// col_fix + integrated base scan (one block per bucket-column)
__global__ __launch_bounds__(256) void col_fix_base(int* __restrict__ blockCounts,
                                                    const int* __restrict__ totals,
                                                    int* __restrict__ bucketBase) {
    __shared__ int vals[NBLK];
    __shared__ int sbase;
    int b = blockIdx.x;
    for (int i = threadIdx.x; i < NBLK; i += 256) vals[i] = blockCounts[i * NB2 + b];
    if (threadIdx.x < 64) {   // wave 0: base_b = sum totals[0..b)
        int lane = threadIdx.x;
        int s = 0;
        for (int i = lane; i < b; i += 64) s += totals[i];
#pragma unroll
        for (int off = 32; off >= 1; off >>= 1) s += __shfl_xor(s, off, 64);
        if (lane == 0) {
            sbase = s;
            bucketBase[b] = s;
            if (b == NB2 - 1) bucketBase[NB2] = s + totals[b];   // == N_EDGES
        }
    }
    __syncthreads();
    if (threadIdx.x < 64) {
        int lane  = threadIdx.x;
        int carry = sbase;
        for (int base = 0; base < NBLK; base += 64) {
            int i = base + lane;
            int v = (i < NBLK) ? vals[i] : 0;
            int incl = v;
#pragma unroll
            for (int off = 1; off < 64; off <<= 1) {
                int t = __shfl_up(incl, off, 64);
                if (lane >= off) incl += t;
            }
            if (i < NBLK) vals[i] = carry + incl - v;
            carry += __shfl(incl, 63, 64);
        }
    }
    __syncthreads();
    for (int i = threadIdx.x; i < NBLK; i += 256) blockCounts[i * NB2 + b] = vals[i];
}

// scatter edges into bucket-sorted order, packed (src<<6)|(dst&63)
__global__ __launch_bounds__(256) void bucket_scatter(const int* __restrict__ ei,
                                                      const int* __restrict__ blockCounts,
                                                      unsigned int* __restrict__ bucketPacked) {
    __shared__ int cur[NB2];
    for (int b = threadIdx.x; b < NB2; b += 256)
        cur[b] = blockCounts[blockIdx.x * NB2 + b];
    __syncthreads();
    int base = blockIdx.x * EPB;
    int lim  = min(EPB, N_EDGES - base);
    for (int i = threadIdx.x; i < lim; i += 256) {
        int s = ei[base + i];
        int d = ei[N_EDGES + base + i];
        int pos = atomicAdd(&cur[d >> 6], 1);
        bucketPacked[pos] = ((unsigned int)s << 6) | (unsigned int)(d & 63);
    }
}

// ==== gemm wrapper (layers 1,2) ==============================================
template <int K, bool F32IN>
__global__ __launch_bounds__(256) void gemm_dual_mfma(
    const void* __restrict__ Av,
    const unsigned short* __restrict__ pS,
    const unsigned short* __restrict__ pN,
    float* __restrict__ hs, unsigned char* __restrict__ hnq) {
    gemm_body<K, F32IN>(Av, pS, pN, hs, hnq, blockIdx.x);
}

// ==== bucket-parallel aggregate + update (+ optional fused MLP) ==============
// One block per 64-node bucket. Edge features accumulated into padded LDS
// fp32 accumulators via ds_add_f32 (no shuffles, no CSR fine-scatter).
template <bool MLP>
__global__ __launch_bounds__(256) void bucket_agg(
    const unsigned int* __restrict__ bucketPacked, const int* __restrict__ bucketBase,
    const unsigned char* __restrict__ hnq, const float* __restrict__ hs,
    unsigned short* __restrict__ hb_out,
    const float* __restrict__ mw1, const float* __restrict__ mb1,
    const float* __restrict__ mw2, const float* __restrict__ mb2,
    float* __restrict__ out) {
    __shared__ float accf[64 * ASTR];
    __shared__ int   cnt[64];
    __shared__ float sc[64];
    __shared__ float sW1[MLP ? HID * 32 : 1];
    __shared__ float sW2[MLP ? 32 : 1];
    __shared__ float sB1[MLP ? 32 : 1];
    int tid = threadIdx.x;
    for (int i = tid; i < 64 * ASTR; i += 256) accf[i] = 0.f;
    if (tid < 64) cnt[tid] = 0;
    if (MLP) {
        for (int i = tid; i < HID * 32; i += 256) sW1[i] = mw1[i];
        if (tid < 32) { sW2[tid] = mw2[tid]; sB1[tid] = mb1[tid]; }
    }
    __syncthreads();

    int beg = bucketBase[blockIdx.x], end = bucketBase[blockIdx.x + 1];
    int n = end - beg;
    int slot = tid >> 3;   // 0..31: edge slot within a 32-edge group
    int r    = tid & 7;    // 8B chunk of the 64B fp8 row

    int b = 0;
    for (; b + 128 <= n; b += 128) {   // 4x unrolled: 4 independent load chains
        unsigned int w[4]; uint2 q[4];
#pragma unroll
        for (int u = 0; u < 4; ++u) w[u] = bucketPacked[beg + b + u * 32 + slot];
#pragma unroll
        for (int u = 0; u < 4; ++u)
            q[u] = *(const uint2*)(hnq + ((size_t)(w[u] >> 6)) * HID + r * 8);
#pragma unroll
        for (int u = 0; u < 4; ++u) {
            int d = w[u] & 63;
            float* ap = accf + d * ASTR + r * 8;
            f32x2 c0 = fp8pair<false>((int)q[u].x), c1 = fp8pair<true>((int)q[u].x);
            f32x2 c2 = fp8pair<false>((int)q[u].y), c3 = fp8pair<true>((int)q[u].y);
            atomicAdd(ap + 0, c0[0]); atomicAdd(ap + 1, c0[1]);
            atomicAdd(ap + 2, c1[0]); atomicAdd(ap + 3, c1[1]);
            atomicAdd(ap + 4, c2[0]); atomicAdd(ap + 5, c2[1]);
            atomicAdd(ap + 6, c3[0]); atomicAdd(ap + 7, c3[1]);
            if (r == 0) atomicAdd(&cnt[d], 1);
        }
    }
    for (; b < n; b += 32) {   // tail
        int e = b + slot;
        if (e < n) {
            unsigned int w = bucketPacked[beg + e];
            uint2 q = *(const uint2*)(hnq + ((size_t)(w >> 6)) * HID + r * 8);
            int d = w & 63;
            float* ap = accf + d * ASTR + r * 8;
            f32x2 c0 = fp8pair<false>((int)q.x), c1 = fp8pair<true>((int)q.x);
            f32x2 c2 = fp8pair<false>((int)q.y), c3 = fp8pair<true>((int)q.y);
            atomicAdd(ap + 0, c0[0]); atomicAdd(ap + 1, c0[1]);
            atomicAdd(ap + 2, c1[0]); atomicAdd(ap + 3, c1[1]);
            atomicAdd(ap + 4, c2[0]); atomicAdd(ap + 5, c2[1]);
            atomicAdd(ap + 6, c3[0]); atomicAdd(ap + 7, c3[1]);
            if (r == 0) atomicAdd(&cnt[d], 1);
        }
    }
    __syncthreads();

    int gbase = blockIdx.x * 64;
    // pass 1: v = relu(acc*invdeg + hs), stored back into accf
#pragma unroll
    for (int m = 0; m < 16; ++m) {
        int i = m * 256 + tid;
        int node = i >> 6, feat = i & 63;
        int gnode = gbase + node;
        if (gnode < N_NODES) {
            float invdeg = 1.0f / fmaxf((float)cnt[node], 1.0f);
            float v = fmaxf(fmaf(accf[node * ASTR + feat], invdeg,
                                 hs[(size_t)gnode * HID + feat]), 0.f);
            accf[node * ASTR + feat] = v;
        }
    }
    __syncthreads();
    // pass 2: per-node norm scale
    if (tid < 64) {
        float ss = 0.f;
        const float* vp = accf + tid * ASTR;
#pragma unroll
        for (int k = 0; k < 64; k += 4) {
            f32x4 v4 = *(const f32x4*)(vp + k);
            ss += v4[0] * v4[0] + v4[1] * v4[1] + v4[2] * v4[2] + v4[3] * v4[3];
        }
        sc[tid] = 1.0f / (sqrtf(ss) + EPS);
    }
    __syncthreads();

    if (!MLP) {
        // pass 3: write normalized bf16 h
#pragma unroll
        for (int m = 0; m < 16; ++m) {
            int i = m * 256 + tid;
            int node = i >> 6, feat = i & 63;
            int gnode = gbase + node;
            if (gnode < N_NODES)
                hb_out[(size_t)gnode * HID + feat] = f2bf(accf[node * ASTR + feat] * sc[node]);
        }
    } else {
        // fused MLP head: 4 threads per node, 8 hidden units each
        int nd = tid >> 2, q4 = tid & 3;
        int gnode = gbase + nd;
        float a[8];
#pragma unroll
        for (int j = 0; j < 8; ++j) a[j] = sB1[q4 * 8 + j];
        float scn = sc[nd];
        const float* hp = accf + nd * ASTR;
        for (int k = 0; k < HID; ++k) {
            float hk = hp[k] * scn;
            f32x4 w0 = *(const f32x4*)(sW1 + k * 32 + q4 * 8);
            f32x4 w1 = *(const f32x4*)(sW1 + k * 32 + q4 * 8 + 4);
#pragma unroll
            for (int j = 0; j < 4; ++j) a[j]     = fmaf(hk, w0[j], a[j]);
#pragma unroll
            for (int j = 0; j < 4; ++j) a[j + 4] = fmaf(hk, w1[j], a[j + 4]);
        }
        float p = 0.f;
#pragma unroll
        for (int j = 0; j < 8; ++j) p += fmaxf(a[j], 0.f) * sW2[q4 * 8 + j];
        p += __shfl_xor(p, 1, 64);
        p += __shfl_xor(p, 2, 64);
        if (q4 == 0 && gnode < N_NODES)
            out[gnode] = 1.0f / (1.0f + __expf(-(p + mb2[0])));
    }
}

extern "C" void kernel_launch(void* const* d_in, const int* in_sizes, int n_in,
                              void* d_out, int out_size, void* d_ws, size_t ws_size,
                              hipStream_t stream) {
    const float* x   = (const float*)d_in[0];
    const int*   ei  = (const int*)d_in[1];
    const float* w0s = (const float*)d_in[2];
    const float* w0n = (const float*)d_in[3];
    const float* w1s = (const float*)d_in[4];
    const float* w1n = (const float*)d_in[5];
    const float* w2s = (const float*)d_in[6];
    const float* w2n = (const float*)d_in[7];
    const float* mw1 = (const float*)d_in[8];
    const float* mb1 = (const float*)d_in[9];
    const float* mw2 = (const float*)d_in[10];
    const float* mb2 = (const float*)d_in[11];
    float*       out = (float*)d_out;

    // ---- workspace layout (all sections 16B aligned) ----
    int* blockCounts = (int*)d_ws;               // NBLK*NB2 = 305762 (pad 306176)
    int* bucketBase  = blockCounts + 306176;     // 1024 (>= NB2+1)
    int* totals      = bucketBase + 1024;        // 1024
    unsigned int* bucketPacked = (unsigned int*)(totals + 1024);   // 1.6M uint (6.4MB)
    const size_t NH = (size_t)N_NODES * HID;
    float*          hs  = (float*)(bucketPacked + N_EDGES);        // NH f32
    unsigned char*  hnq = (unsigned char*)(hs + NH);               // NH fp8
    unsigned short* hb  = (unsigned short*)(hnq + NH);             // NH bf16
    unsigned short* p0S = hb + NH;               // 128*64
    unsigned short* p0N = p0S + IN_DIM * HID;
    unsigned short* p1S = p0N + IN_DIM * HID;    // 64*64
    unsigned short* p1N = p1S + HID * HID;
    unsigned short* p2S = p1N + HID * HID;
    unsigned short* p2N = p2S + HID * HID;
    // total ~29 MB

    const int gemmGrid = (N_NODES / 16 + 3) / 4; // 782

    // ---- bucket sort + weight pack + layer-0 GEMM (packed into dispatches) ----
    bucket_count_pack<<<NBLK + 8, 256, 0, stream>>>(
        ei, blockCounts, w0s, w0n, w1s, w1n, w2s, w2n,
        p0S, p0N, p1S, p1N, p2S, p2N);
    col_sum_gemm0<<<NB2 + gemmGrid, 256, 0, stream>>>(
        blockCounts, totals, x, p0S, p0N, hs, hnq);
    col_fix_base<<<NB2, 256, 0, stream>>>(blockCounts, totals, bucketBase);
    bucket_scatter<<<NBLK, 256, 0, stream>>>(ei, blockCounts, bucketPacked);

    // ---- layer 0 aggregate (gemm L0 already done in col_sum dispatch) ----
    bucket_agg<false><<<NB2, 256, 0, stream>>>(
        bucketPacked, bucketBase, hnq, hs, hb, nullptr, nullptr, nullptr, nullptr, nullptr);

    // ---- layer 1 ----
    gemm_dual_mfma<HID, false><<<gemmGrid, 256, 0, stream>>>(hb, p1S, p1N, hs, hnq);
    bucket_agg<false><<<NB2, 256, 0, stream>>>(
        bucketPacked, bucketBase, hnq, hs, hb, nullptr, nullptr, nullptr, nullptr, nullptr);

    // ---- layer 2 (+ fused MLP head) ----
    gemm_dual_mfma<HID, false><<<gemmGrid, 256, 0, stream>>>(hb, p2S, p2N, hs, hnq);
    bucket_agg<true><<<NB2, 256, 0, stream>>>(
        bucketPacked, bucketBase, hnq, hs, nullptr, mw1, mb1, mw2, mb2, out);
}

// Round 13
// 277.320 us; speedup vs baseline: 7.9698x; 7.9698x over previous
//
#include <hip/hip_runtime.h>
#include <hip/hip_bf16.h>
#include <math.h>

#define N_NODES 50000
#define N_EDGES 1600000
#define IN_DIM  128
#define HID     64
#define EPB     4096   // edges per sort block
#define NBLK    391    // ceil(N_EDGES / EPB)
#define NB      391    // ceil(N_NODES / 128) buckets of 128 nodes
#define CAP     8192   // LDS staging capacity (edges/bucket; mean 4092)
static constexpr float EPS = 1e-6f;

typedef __attribute__((ext_vector_type(8))) short          short8;   // 8 bf16
typedef __attribute__((ext_vector_type(8))) unsigned short ushort8;
typedef __attribute__((ext_vector_type(4))) float          f32x4;
typedef __attribute__((ext_vector_type(2))) float          f32x2;

__device__ __forceinline__ unsigned short f2bf(float f) {   // round-nearest-even
    union { float f; unsigned int i; } c; c.f = f;
    unsigned int r = c.i + 0x7FFFu + ((c.i >> 16) & 1u);
    return (unsigned short)(r >> 16);
}
__device__ __forceinline__ unsigned char f2fp8(float f) {   // OCP e4m3, HW cvt
    int p = __builtin_amdgcn_cvt_pk_fp8_f32(f, f, 0, false);
    return (unsigned char)(p & 0xff);
}
// hi-half selector must be a compile-time constant -> template parameter
template <bool HI>
__device__ __forceinline__ f32x2 fp8pair(int w) {
#if __has_builtin(__builtin_amdgcn_cvt_pk_f32_fp8)
    return __builtin_amdgcn_cvt_pk_f32_fp8(w, HI);
#else
    return (f32x2){__builtin_amdgcn_cvt_f32_fp8(w, HI ? 2 : 0),
                   __builtin_amdgcn_cvt_f32_fp8(w, HI ? 3 : 1)};
#endif
}

// ==== weight packing =========================================================

template <int K>
__device__ __forceinline__ void pack_body(const float* __restrict__ wS,
                                          const float* __restrict__ wN,
                                          unsigned short* __restrict__ pS,
                                          unsigned short* __restrict__ pN, int blk) {
    constexpr int NSLOT = (K / 32) * 4 * 64;
    int slot = blk * 256 + (int)threadIdx.x;
    if (slot >= NSLOT) return;
    int lane = slot & 63;
    int ct   = slot >> 6;
    int t    = ct & 3;
    int c    = ct >> 2;
    int m    = lane & 15;
    int quad = lane >> 4;
    int col  = t * 16 + m;
#pragma unroll
    for (int j = 0; j < 8; ++j) {
        int k = c * 32 + quad * 8 + j;
        pS[slot * 8 + j] = f2bf(wS[k * 64 + col]);
        pN[slot * 8 + j] = f2bf(wN[k * 64 + col]);
    }
}

// ==== CSR build: binned counting sort ========================================

// blocks 0..NBLK-1: per-block bucket histogram; blocks NBLK..NBLK+7: weight pack
__global__ __launch_bounds__(256) void bucket_count_pack(
    const int* __restrict__ ei, int* __restrict__ blockCounts,
    const float* __restrict__ w0s, const float* __restrict__ w0n,
    const float* __restrict__ w1s, const float* __restrict__ w1n,
    const float* __restrict__ w2s, const float* __restrict__ w2n,
    unsigned short* __restrict__ p0S, unsigned short* __restrict__ p0N,
    unsigned short* __restrict__ p1S, unsigned short* __restrict__ p1N,
    unsigned short* __restrict__ p2S, unsigned short* __restrict__ p2N) {
    if (blockIdx.x >= NBLK) {
        int blk = blockIdx.x - NBLK;
        if (blk < 4)      pack_body<IN_DIM>(w0s, w0n, p0S, p0N, blk);
        else if (blk < 6) pack_body<HID>(w1s, w1n, p1S, p1N, blk - 4);
        else              pack_body<HID>(w2s, w2n, p2S, p2N, blk - 6);
        return;
    }
    __shared__ int hist[NB];
    for (int i = threadIdx.x; i < NB; i += 256) hist[i] = 0;
    __syncthreads();
    int base = blockIdx.x * EPB;
    int lim  = min(EPB, N_EDGES - base);
    for (int i = threadIdx.x; i < lim; i += 256)
        atomicAdd(&hist[ei[N_EDGES + base + i] >> 7], 1);
    __syncthreads();
    for (int b = threadIdx.x; b < NB; b += 256)
        blockCounts[blockIdx.x * NB + b] = hist[b];
}

// ==== dual GEMM body =========================================================
// hs = A@wS (fp32 out), hn = A@wN (fp8 e4m3 out)
template <int K, bool F32IN>
__device__ __forceinline__ void gemm_body(
    const void* __restrict__ Av,
    const unsigned short* __restrict__ pS,
    const unsigned short* __restrict__ pN,
    float* __restrict__ hs, unsigned char* __restrict__ hnq, int blk) {
    constexpr int NC = K / 32;
    int lane = threadIdx.x & 63;
    int wv   = threadIdx.x >> 6;
    int tile = blk * 4 + wv;
    if (tile >= N_NODES / 16) return;
    int m    = lane & 15;
    int quad = lane >> 4;

    const short8* pSf = (const short8*)pS;
    const short8* pNf = (const short8*)pN;

    f32x4 accS[4], accN[4];
#pragma unroll
    for (int t = 0; t < 4; ++t) {
        accS[t] = (f32x4){0.f, 0.f, 0.f, 0.f};
        accN[t] = (f32x4){0.f, 0.f, 0.f, 0.f};
    }
#pragma unroll
    for (int c = 0; c < NC; ++c) {
        short8 a;
        if constexpr (F32IN) {
            const float* Af = (const float*)Av + ((size_t)tile * 16 + m) * K + quad * 8 + c * 32;
            f32x4 a0 = *(const f32x4*)Af;
            f32x4 a1 = *(const f32x4*)(Af + 4);
#pragma unroll
            for (int k = 0; k < 4; ++k) a[k]     = (short)f2bf(a0[k]);
#pragma unroll
            for (int k = 0; k < 4; ++k) a[k + 4] = (short)f2bf(a1[k]);
        } else {
            const short8* Af = (const short8*)((const unsigned short*)Av +
                               ((size_t)tile * 16 + m) * K + quad * 8);
            a = Af[c * 4];
        }
#pragma unroll
        for (int t = 0; t < 4; ++t) {
            short8 bs = pSf[(c * 4 + t) * 64 + lane];
            short8 bn = pNf[(c * 4 + t) * 64 + lane];
            accS[t] = __builtin_amdgcn_mfma_f32_16x16x32_bf16(a, bs, accS[t], 0, 0, 0);
            accN[t] = __builtin_amdgcn_mfma_f32_16x16x32_bf16(a, bn, accN[t], 0, 0, 0);
        }
    }
    int row0 = tile * 16 + quad * 4;
#pragma unroll
    for (int t = 0; t < 4; ++t) {
#pragma unroll
        for (int r = 0; r < 4; ++r) {
            size_t o = (size_t)(row0 + r) * HID + t * 16 + m;
            hs[o]  = accS[t][r];
            hnq[o] = f2fp8(accN[t][r]);
        }
    }
}

// blocks 0..NB-1: col_sum; blocks NB.. : layer-0 GEMM (independent work overlap)
__global__ __launch_bounds__(256) void col_sum_gemm0(
    const int* __restrict__ blockCounts, int* __restrict__ totals,
    const float* __restrict__ x,
    const unsigned short* __restrict__ p0S, const unsigned short* __restrict__ p0N,
    float* __restrict__ hs, unsigned char* __restrict__ hnq) {
    if (blockIdx.x >= NB) {
        gemm_body<IN_DIM, true>(x, p0S, p0N, hs, hnq, blockIdx.x - NB);
        return;
    }
    __shared__ int ws[4];
    int b = blockIdx.x;
    int s = 0;
    for (int i = threadIdx.x; i < NBLK; i += 256) s += blockCounts[i * NB + b];
#pragma unroll
    for (int off = 32; off >= 1; off >>= 1) s += __shfl_xor(s, off, 64);
    if ((threadIdx.x & 63) == 0) ws[threadIdx.x >> 6] = s;
    __syncthreads();
    if (threadIdx.x == 0) totals[b] = ws[0] + ws[1] + ws[2] + ws[3];
}

// col_fix + integrated base scan
__global__ __launch_bounds__(256) void col_fix_base(int* __restrict__ blockCounts,
                                                    const int* __restrict__ totals,
                                                    int* __restrict__ bucketBase) {
    __shared__ int vals[NBLK];
    __shared__ int sbase;
    int b = blockIdx.x;
    for (int i = threadIdx.x; i < NBLK; i += 256) vals[i] = blockCounts[i * NB + b];
    if (threadIdx.x < 64) {   // wave 0: base_b = sum totals[0..b)
        int lane = threadIdx.x;
        int s = 0;
        for (int i = lane; i < b; i += 64) s += totals[i];
#pragma unroll
        for (int off = 32; off >= 1; off >>= 1) s += __shfl_xor(s, off, 64);
        if (lane == 0) {
            sbase = s;
            bucketBase[b] = s;
            if (b == NB - 1) bucketBase[NB] = s + totals[b];   // == N_EDGES
        }
    }
    __syncthreads();
    if (threadIdx.x < 64) {
        int lane  = threadIdx.x;
        int carry = sbase;
        for (int base = 0; base < NBLK; base += 64) {
            int i = base + lane;
            int v = (i < NBLK) ? vals[i] : 0;
            int incl = v;
#pragma unroll
            for (int off = 1; off < 64; off <<= 1) {
                int t = __shfl_up(incl, off, 64);
                if (lane >= off) incl += t;
            }
            if (i < NBLK) vals[i] = carry + incl - v;
            carry += __shfl(incl, 63, 64);
        }
    }
    __syncthreads();
    for (int i = threadIdx.x; i < NBLK; i += 256) blockCounts[i * NB + b] = vals[i];
}

// scatter edges into bucket-sorted order, packed (src<<7)|(dst&127)
__global__ __launch_bounds__(256) void bucket_scatter(const int* __restrict__ ei,
                                                      const int* __restrict__ blockCounts,
                                                      unsigned int* __restrict__ bucketPacked) {
    __shared__ int cur[NB];
    for (int b = threadIdx.x; b < NB; b += 256)
        cur[b] = blockCounts[blockIdx.x * NB + b];
    __syncthreads();
    int base = blockIdx.x * EPB;
    int lim  = min(EPB, N_EDGES - base);
    for (int i = threadIdx.x; i < lim; i += 256) {
        int s = ei[base + i];
        int d = ei[N_EDGES + base + i];
        int pos = atomicAdd(&cur[d >> 7], 1);
        bucketPacked[pos] = ((unsigned int)s << 7) | (unsigned int)(d & 127);
    }
}

// fused: per-bucket degree count -> in-bucket scan -> rowptr -> local scatter.
__global__ __launch_bounds__(256) void node_scan_scatter(
    const unsigned int* __restrict__ bucketPacked, const int* __restrict__ bucketBase,
    int* __restrict__ rowptr, int* __restrict__ csr_src) {
    __shared__ int cnt[128];
    __shared__ int half0;
    __shared__ unsigned int stage[CAP];
    int tid = threadIdx.x;
    if (tid < 128) cnt[tid] = 0;
    __syncthreads();
    int beg = bucketBase[blockIdx.x], end = bucketBase[blockIdx.x + 1];
    int n = end - beg;
    for (int i = tid; i < n; i += 256) {
        unsigned int e = bucketPacked[beg + i];
        if (i < CAP) stage[i] = e;
        atomicAdd(&cnt[e & 127], 1);
    }
    __syncthreads();
    int lane = tid & 63;
    int v    = (tid < 128) ? cnt[tid] : 0;
    int incl = v;
#pragma unroll
    for (int off = 1; off < 64; off <<= 1) {
        int t = __shfl_up(incl, off, 64);
        if (lane >= off) incl += t;
    }
    if (tid == 63) half0 = incl;
    __syncthreads();
    int base  = beg + ((tid >= 64 && tid < 128) ? half0 : 0);
    int start = base + incl - v;
    int node  = blockIdx.x * 128 + tid;
    if (tid < 128) {
        if (node < N_NODES) rowptr[node] = start;
        cnt[tid] = start;   // becomes the scatter cursor
    }
    if (blockIdx.x == 0 && tid == 128) rowptr[N_NODES] = N_EDGES;
    __syncthreads();
    for (int i = tid; i < n; i += 256) {
        unsigned int e = (i < CAP) ? stage[i] : bucketPacked[beg + i];
        int pos = atomicAdd(&cnt[e & 127], 1);
        csr_src[pos] = (int)(e >> 7);
    }
}

// ==== gemm wrapper (layers 1,2) ==============================================
template <int K, bool F32IN>
__global__ __launch_bounds__(256) void gemm_dual_mfma(
    const void* __restrict__ Av,
    const unsigned short* __restrict__ pS,
    const unsigned short* __restrict__ pN,
    float* __restrict__ hs, unsigned char* __restrict__ hnq) {
    gemm_body<K, F32IN>(Av, pS, pN, hs, hnq, blockIdx.x);
}

// ==== fused gather-aggregate + update (+ optional MLP head) ==================
// g = lane>>3 (8 edge slots), r = lane&7 (8B chunk of the 64B fp8 row).
// Index broadcast via direct VMEM loads (L1 same-address broadcast) instead of
// ds_bpermute — removes the serial LGKM dependency in front of every gather.
template <bool MLP>
__global__ __launch_bounds__(256) void agg_update(
    const int* __restrict__ rowptr, const int* __restrict__ csr_src,
    const unsigned char* __restrict__ hnq, const float* __restrict__ hs,
    unsigned short* __restrict__ hb_out,
    const float* __restrict__ mw1, const float* __restrict__ mb1,
    const float* __restrict__ mw2, const float* __restrict__ mb2,
    float* __restrict__ out) {
    __shared__ float sW1[MLP ? HID * 32 : 1];
    __shared__ float sW2[MLP ? 32 : 1];
    __shared__ float sB1[MLP ? 32 : 1];
    __shared__ float sH[MLP ? 4 * HID : 1];
    if (MLP) {
        for (int i = threadIdx.x; i < HID * 32; i += 256) sW1[i] = mw1[i];
        if (threadIdx.x < 32) { sW2[threadIdx.x] = mw2[threadIdx.x]; sB1[threadIdx.x] = mb1[threadIdx.x]; }
        __syncthreads();
    }
    int node = (blockIdx.x * 256 + threadIdx.x) >> 6;   // grid covers exactly N_NODES
    int lane = threadIdx.x & 63;
    int g = lane >> 3;   // edge slot 0..7
    int r = lane & 7;    // 8B chunk 0..7
    int beg = rowptr[node];
    int end = rowptr[node + 1];
    f32x2 acc2[4];
#pragma unroll
    for (int k = 0; k < 4; ++k) acc2[k] = (f32x2){0.f, 0.f};
    int e = beg;
    for (; e + 32 <= end; e += 32) {   // 4 independent load chains
        int s0 = csr_src[e + g];
        int s1 = csr_src[e + 8 + g];
        int s2 = csr_src[e + 16 + g];
        int s3 = csr_src[e + 24 + g];
        uint2 w0 = *(const uint2*)(hnq + (size_t)s0 * HID + r * 8);
        uint2 w1 = *(const uint2*)(hnq + (size_t)s1 * HID + r * 8);
        uint2 w2 = *(const uint2*)(hnq + (size_t)s2 * HID + r * 8);
        uint2 w3 = *(const uint2*)(hnq + (size_t)s3 * HID + r * 8);
        acc2[0] += fp8pair<false>((int)w0.x); acc2[1] += fp8pair<true>((int)w0.x);
        acc2[2] += fp8pair<false>((int)w0.y); acc2[3] += fp8pair<true>((int)w0.y);
        acc2[0] += fp8pair<false>((int)w1.x); acc2[1] += fp8pair<true>((int)w1.x);
        acc2[2] += fp8pair<false>((int)w1.y); acc2[3] += fp8pair<true>((int)w1.y);
        acc2[0] += fp8pair<false>((int)w2.x); acc2[1] += fp8pair<true>((int)w2.x);
        acc2[2] += fp8pair<false>((int)w2.y); acc2[3] += fp8pair<true>((int)w2.y);
        acc2[0] += fp8pair<false>((int)w3.x); acc2[1] += fp8pair<true>((int)w3.x);
        acc2[2] += fp8pair<false>((int)w3.y); acc2[3] += fp8pair<true>((int)w3.y);
    }
    for (; e < end; e += 8) {   // tail: up to 8 edges, one per g slot
        if (g < end - e) {
            int s = csr_src[e + g];
            uint2 w = *(const uint2*)(hnq + (size_t)s * HID + r * 8);
            acc2[0] += fp8pair<false>((int)w.x); acc2[1] += fp8pair<true>((int)w.x);
            acc2[2] += fp8pair<false>((int)w.y); acc2[3] += fp8pair<true>((int)w.y);
        }
    }
    float acc[8];
#pragma unroll
    for (int k = 0; k < 4; ++k) { acc[2 * k] = acc2[k][0]; acc[2 * k + 1] = acc2[k][1]; }
    // reduce across g (masks 8,16,32)
#pragma unroll
    for (int k = 0; k < 8; ++k) {
        acc[k] += __shfl_xor(acc[k], 8, 64);
        acc[k] += __shfl_xor(acc[k], 16, 64);
        acc[k] += __shfl_xor(acc[k], 32, 64);
    }
    float invdeg = 1.0f / fmaxf((float)(end - beg), 1.0f);
    const float* hsr = hs + (size_t)node * HID + r * 8;
    f32x4 h0 = *(const f32x4*)hsr;
    f32x4 h1 = *(const f32x4*)(hsr + 4);
    float v[8], ss = 0.f;
#pragma unroll
    for (int k = 0; k < 8; ++k) {
        float hk = (k < 4) ? h0[k] : h1[k - 4];
        v[k] = fmaxf(fmaf(acc[k], invdeg, hk), 0.f);
        ss += v[k] * v[k];
    }
    // reduce across r (masks 1,2,4): full 64-feature sum (g-groups duplicate)
    ss += __shfl_xor(ss, 1, 64);
    ss += __shfl_xor(ss, 2, 64);
    ss += __shfl_xor(ss, 4, 64);
    float rs = 1.0f / (sqrtf(ss) + EPS);
    if (MLP) {
        int wv = threadIdx.x >> 6;
        if (g == 0) {   // lanes 0..7 hold the 64 features (8 each), stage fp32 row
#pragma unroll
            for (int k = 0; k < 8; ++k) sH[wv * HID + r * 8 + k] = v[k] * rs;
        }
        float p = 0.f;
        if (lane < 32) {
            float a2 = sB1[lane];
#pragma unroll
            for (int k = 0; k < HID; ++k) a2 = fmaf(sH[wv * HID + k], sW1[k * 32 + lane], a2);
            p = fmaxf(a2, 0.f) * sW2[lane];
        }
#pragma unroll
        for (int off = 32; off >= 1; off >>= 1) p += __shfl_xor(p, off, 64);
        if (lane == 0) out[node] = 1.0f / (1.0f + __expf(-(p + mb2[0])));
    } else {
        if (g == 0) {   // 8 lanes x 16B = full 128B bf16 row
            ushort8 o;
#pragma unroll
            for (int k = 0; k < 8; ++k) o[k] = f2bf(v[k] * rs);
            *(ushort8*)(hb_out + (size_t)node * HID + r * 8) = o;
        }
    }
}

extern "C" void kernel_launch(void* const* d_in, const int* in_sizes, int n_in,
                              void* d_out, int out_size, void* d_ws, size_t ws_size,
                              hipStream_t stream) {
    const float* x   = (const float*)d_in[0];
    const int*   ei  = (const int*)d_in[1];
    const float* w0s = (const float*)d_in[2];
    const float* w0n = (const float*)d_in[3];
    const float* w1s = (const float*)d_in[4];
    const float* w1n = (const float*)d_in[5];
    const float* w2s = (const float*)d_in[6];
    const float* w2n = (const float*)d_in[7];
    const float* mw1 = (const float*)d_in[8];
    const float* mb1 = (const float*)d_in[9];
    const float* mw2 = (const float*)d_in[10];
    const float* mb2 = (const float*)d_in[11];
    float*       out = (float*)d_out;

    // ---- workspace layout (all sections 16B aligned) ----
    int* rowptr      = (int*)d_ws;               // 50432 (>= N+1)
    int* csr_src     = rowptr + 50432;           // 1.6M
    int* blockCounts = csr_src + N_EDGES;        // NBLK*NB = 152881 (pad 153600)
    int* bucketBase  = blockCounts + 153600;     // 512
    int* totals      = bucketBase + 512;         // 512
    unsigned int* bucketPacked = (unsigned int*)(totals + 512);   // 1.6M uint (6.4MB)
    const size_t NH = (size_t)N_NODES * HID;
    float*          hs  = (float*)(bucketPacked + N_EDGES);       // NH f32
    unsigned char*  hnq = (unsigned char*)(hs + NH);              // NH fp8
    unsigned short* hb  = (unsigned short*)(hnq + NH);            // NH bf16
    unsigned short* p0S = hb + NH;               // 128*64
    unsigned short* p0N = p0S + IN_DIM * HID;
    unsigned short* p1S = p0N + IN_DIM * HID;    // 64*64
    unsigned short* p1N = p1S + HID * HID;
    unsigned short* p2S = p1N + HID * HID;
    unsigned short* p2N = p2S + HID * HID;
    // total ~36 MB

    const int nodeGrid = (N_NODES * HID) / 256;  // 12500 (covers nodes exactly)
    const int gemmGrid = (N_NODES / 16 + 3) / 4; // 782

    // ---- CSR build + weight pack + layer-0 GEMM (packed into idle dispatches) ----
    bucket_count_pack<<<NBLK + 8, 256, 0, stream>>>(
        ei, blockCounts, w0s, w0n, w1s, w1n, w2s, w2n,
        p0S, p0N, p1S, p1N, p2S, p2N);
    col_sum_gemm0<<<NB + gemmGrid, 256, 0, stream>>>(
        blockCounts, totals, x, p0S, p0N, hs, hnq);
    col_fix_base<<<NB, 256, 0, stream>>>(blockCounts, totals, bucketBase);
    bucket_scatter<<<NBLK, 256, 0, stream>>>(ei, blockCounts, bucketPacked);
    node_scan_scatter<<<NB, 256, 0, stream>>>(bucketPacked, bucketBase, rowptr, csr_src);

    // ---- layer 0 aggregate (gemm L0 already done in col_sum dispatch) ----
    agg_update<false><<<nodeGrid, 256, 0, stream>>>(
        rowptr, csr_src, hnq, hs, hb, nullptr, nullptr, nullptr, nullptr, nullptr);

    // ---- layer 1 ----
    gemm_dual_mfma<HID, false><<<gemmGrid, 256, 0, stream>>>(hb, p1S, p1N, hs, hnq);
    agg_update<false><<<nodeGrid, 256, 0, stream>>>(
        rowptr, csr_src, hnq, hs, hb, nullptr, nullptr, nullptr, nullptr, nullptr);

    // ---- layer 2 (+ fused MLP head) ----
    gemm_dual_mfma<HID, false><<<gemmGrid, 256, 0, stream>>>(hb, p2S, p2N, hs, hnq);
    agg_update<true><<<nodeGrid, 256, 0, stream>>>(
        rowptr, csr_src, hnq, hs, nullptr, mw1, mb1, mw2, mb2, out);
}